// Round 5
// baseline (424.198 us; speedup 1.0000x reference)
//
#include <hip/hip_runtime.h>

typedef short  s16x8  __attribute__((ext_vector_type(8)));
typedef float  f32x16 __attribute__((ext_vector_type(16)));
typedef unsigned short u16;
typedef unsigned long long u64b;

#define MFMA32(a,b,c) __builtin_amdgcn_mfma_f32_32x32x16_bf16((a),(b),(c),0,0,0)
#define KCLS 100

__device__ __forceinline__ u16 f2bf(float f) {
  return (u16)(__builtin_bit_cast(unsigned, f) >> 16);   // trunc; error budget huge
}

__device__ __forceinline__ float tanh_fast(float x) {
  float e = __builtin_amdgcn_exp2f(x * 2.8853900817779268f);
  return 1.0f - 2.0f * __builtin_amdgcn_rcpf(e + 1.0f);
}

// ============ prep: emit fragment-ordered bf16 tensors + zero accumulators ============
// Fragment = 1 KB: [lane64][8 bf16]; lane&31 = row/col-in-tile, lane>>5 = k-half.
// xF  [b][frag = gks*2+ph]   p = ph*32+(lane&31), c = gks*16+(lane>>5)*8+j
// W1F [k][frag = gks*2+mt]   m = mt*32+(lane&31), c as above
// W2F [k][frag = kb*4+m4]    m = m4*32+(lane&31), c = kb*16+(lane>>5)*8+j
// W3F [k][frag = kb]         m = lane&31,         c = kb*16+(lane>>5)*8+j
__global__ void prep(const float* __restrict__ x, const float* __restrict__ w1,
                     const float* __restrict__ w2, const float* __restrict__ w3,
                     u16* __restrict__ xF, u16* __restrict__ W1F,
                     u16* __restrict__ W2F, u16* __restrict__ W3F,
                     float* __restrict__ fz, unsigned* __restrict__ done,
                     float* __restrict__ out2) {
  __shared__ float tile[64][65];
  const int bid = blockIdx.x, t = threadIdx.x;
  if (bid == 0) {
    if (t < 2) out2[t] = 0.f;
    if (t == 2) *done = 0u;
  }
  if (bid < 512) {                                // ---- x: block = (b, ck) ----
    const int b = bid >> 3, ck = bid & 7;
    #pragma unroll
    for (int j = 0; j < 4; j++) {                 // coalesced fp32 tile (64c x 64p)
      int e4 = j * 1024 + t * 4;
      int c = e4 >> 6, p0 = e4 & 63;
      float4 v = *(const float4*)(x + ((size_t)b * 512 + ck * 64 + c) * 64 + p0);
      tile[c][p0] = v.x; tile[c][p0 + 1] = v.y; tile[c][p0 + 2] = v.z; tile[c][p0 + 3] = v.w;
    }
    __syncthreads();
    #pragma unroll
    for (int i = 0; i < 2; i++) {                 // 512 16B-slots
      int s = i * 256 + t;
      int ksl = s >> 7, ph = (s >> 6) & 1, lane = s & 63;
      int cb = ksl * 16 + (lane >> 5) * 8, pp = ph * 32 + (lane & 31);
      u16 o[8];
      #pragma unroll
      for (int jj = 0; jj < 8; jj++) o[jj] = f2bf(tile[cb + jj][pp]);
      *(uint4*)(xF + (((size_t)b * 64 + (ck * 4 + ksl) * 2 + ph) * 512) + lane * 8) = *(uint4*)o;
    }
  } else if (bid < 1312) {                        // ---- W1: 6400 frags ----
    int base = (bid - 512) * 512;
    #pragma unroll
    for (int i = 0; i < 2; i++) {
      int s = base + i * 256 + t;
      int frag = s >> 6, lane = s & 63;
      int k = frag >> 6, fr = frag & 63;
      int m = (fr & 1) * 32 + (lane & 31);
      int c0 = (fr >> 1) * 16 + (lane >> 5) * 8;
      const float* src = w1 + ((size_t)k * 64 + m) * 512 + c0;
      float4 a = *(const float4*)src, b4 = *(const float4*)(src + 4);
      u16 o[8] = { f2bf(a.x), f2bf(a.y), f2bf(a.z), f2bf(a.w),
                   f2bf(b4.x), f2bf(b4.y), f2bf(b4.z), f2bf(b4.w) };
      *(uint4*)(W1F + ((size_t)frag * 512) + lane * 8) = *(uint4*)o;
    }
  } else if (bid < 1512) {                        // ---- W2: 1600 frags ----
    int base = (bid - 1312) * 512;
    #pragma unroll
    for (int i = 0; i < 2; i++) {
      int s = base + i * 256 + t;
      int frag = s >> 6, lane = s & 63;
      int k = frag >> 4, fr = frag & 15;
      int m = (fr & 3) * 32 + (lane & 31);
      int c0 = (fr >> 2) * 16 + (lane >> 5) * 8;
      const float* src = w2 + ((size_t)k * 128 + m) * 64 + c0;
      float4 a = *(const float4*)src, b4 = *(const float4*)(src + 4);
      u16 o[8] = { f2bf(a.x), f2bf(a.y), f2bf(a.z), f2bf(a.w),
                   f2bf(b4.x), f2bf(b4.y), f2bf(b4.z), f2bf(b4.w) };
      *(uint4*)(W2F + ((size_t)frag * 512) + lane * 8) = *(uint4*)o;
    }
  } else if (bid < 1612) {                        // ---- W3: 800 frags ----
    int base = (bid - 1512) * 512;
    #pragma unroll
    for (int i = 0; i < 2; i++) {
      int s = base + i * 256 + t;
      int frag = s >> 6, lane = s & 63;
      int k = frag >> 3, kb = frag & 7;
      int m = lane & 31;
      int c0 = kb * 16 + (lane >> 5) * 8;
      const float* src = w3 + ((size_t)k * 32 + m) * 128 + c0;
      float4 a = *(const float4*)src, b4 = *(const float4*)(src + 4);
      u16 o[8] = { f2bf(a.x), f2bf(a.y), f2bf(a.z), f2bf(a.w),
                   f2bf(b4.x), f2bf(b4.y), f2bf(b4.z), f2bf(b4.w) };
      *(uint4*)(W3F + ((size_t)frag * 512) + lane * 8) = *(uint4*)o;
    }
  } else {                                        // ---- zero fw/f1w (12800 floats) ----
    int i4 = (bid - 1612) * 256 + t;
    if (i4 < 3200) {
      float4 z = {0.f, 0.f, 0.f, 0.f};
      *(float4*)(fz + (size_t)i4 * 4) = z;
    }
  }
}

// ============ main: barrier-free per-(k, b-pair); wave-private LDS scratch ============
__global__ __launch_bounds__(256, 4) void cssr_main(
    const u16* __restrict__ W1F, const u16* __restrict__ W2F, const u16* __restrict__ W3F,
    const u16* __restrict__ xF, const float* __restrict__ protos,
    const float* __restrict__ protos1, const int* __restrict__ ycls,
    float* __restrict__ out, float* __restrict__ fw, float* __restrict__ f1w,
    unsigned* __restrict__ done, float* __restrict__ out2)
{
  __shared__ u16 pool[16384];        // 32 KB: 8 KB wave-private scratch x 4 waves
  __shared__ int isLast;

  const int bid = blockIdx.x;
  const int k = bid >> 5, b0 = (bid & 31) * 2;
  const int tid = threadIdx.x, w = tid >> 6, lane = tid & 63;
  const int nhalf = lane >> 5, nn = lane & 31;
  const int b = b0 + (w >> 1), ph = w & 1;   // wave's column strip: batch b, p-half ph

  u16* wls = pool + (w << 12);       // 4096 u16 per wave

  // -------- stage 1: h1 = tanh(W1[k] @ x)  per-wave M=64 N=32 K=512, no barriers ----
  f32x16 acc1[2] = {};
  const u16* xb = xF + (((size_t)b * 64 + ph) * 512) + lane * 8;
  const u16* wA = W1F + ((size_t)k * 64 * 512) + lane * 8;
  #pragma unroll 4
  for (int g = 0; g < 32; g++) {
    s16x8 B  = *(const s16x8*)(xb + g * 1024);
    s16x8 A0 = *(const s16x8*)(wA + g * 1024);
    s16x8 A1 = *(const s16x8*)(wA + g * 1024 + 512);
    acc1[0] = MFMA32(A0, B, acc1[0]);
    acc1[1] = MFMA32(A1, B, acc1[1]);
  }

  // handoff 1 (intra-wave): C/D (m = mt*32 + q+8g+4*nhalf) -> B-frags wls[kb]
  #pragma unroll
  for (int mt = 0; mt < 2; mt++) {
    #pragma unroll
    for (int g = 0; g < 4; g++) {
      u16 hv[4];
      #pragma unroll
      for (int q = 0; q < 4; q++) hv[q] = f2bf(tanh_fast(acc1[mt][g * 4 + q]));
      int kb = mt * 2 + (g >> 1);
      int tl = (g & 1) * 32 + nn;
      *(u64b*)&wls[kb * 512 + tl * 8 + nhalf * 4] = *(u64b*)hv;
    }
  }

  // -------- stage 2: h2 = tanh(W2[k] @ h1)  per-wave M=128 N=32 K=64 ----------
  f32x16 acc2[4] = {};
  #pragma unroll
  for (int kb = 0; kb < 4; kb++) {
    s16x8 B = *(const s16x8*)&wls[kb * 512 + lane * 8];
    #pragma unroll
    for (int m4 = 0; m4 < 4; m4++) {
      s16x8 A = *(const s16x8*)(W2F + (((size_t)k * 16) + kb * 4 + m4) * 512 + lane * 8);
      acc2[m4] = MFMA32(A, B, acc2[m4]);
    }
  }

  // handoff 2 (intra-wave, overwrites wls after all stage-2 reads)
  #pragma unroll
  for (int m4 = 0; m4 < 4; m4++) {
    #pragma unroll
    for (int g = 0; g < 4; g++) {
      u16 hv[4];
      #pragma unroll
      for (int q = 0; q < 4; q++) hv[q] = f2bf(tanh_fast(acc2[m4][g * 4 + q]));
      int kb2 = m4 * 2 + (g >> 1);
      int tl  = (g & 1) * 32 + nn;
      *(u64b*)&wls[kb2 * 512 + tl * 8 + nhalf * 4] = *(u64b*)hv;
    }
  }

  // -------- stage 3: lt = tanh(W3[k] @ h2)  per-wave M=32 N=32 K=128 ----------
  f32x16 acc3 = {};
  #pragma unroll
  for (int kb = 0; kb < 8; kb++) {
    s16x8 A = *(const s16x8*)(W3F + (((size_t)k * 8) + kb) * 512 + lane * 8);
    s16x8 B = *(const s16x8*)&wls[kb * 512 + lane * 8];
    acc3 = MFMA32(A, B, acc3);
  }

  // -------- distances, clip, logits, f/f1 ----------
  const int p = ph * 32 + nn;
  const float* pr  = protos  + (size_t)k * 2048;
  const float* pr1 = protos1 + (size_t)k * 2048;
  float d2 = 0.f, d21 = 0.f;
  #pragma unroll
  for (int g = 0; g < 4; g++) {
    #pragma unroll
    for (int q = 0; q < 4; q++) {
      int m = q + 8 * g + 4 * nhalf;
      float lt = tanh_fast(acc3[g * 4 + q]);
      float d = lt - pr [m * 64 + p];  d2  += d * d;
      float e = lt - pr1[m * 64 + p];  d21 += e * e;
    }
  }
  d2 += __shfl_xor(d2, 32); d21 += __shfl_xor(d21, 32);
  float er  = fminf(fmaxf(d2  * -0.1f, -100.f), 100.f);
  float er1 = fminf(fmaxf(d21 * -0.1f, -100.f), 100.f);
  if (nhalf == 0) {
    out[(size_t)b * 6400 + k * 64 + p]          = er;
    out[409600 + (size_t)b * 6400 + k * 64 + p] = er1;
  }
  float s = er, s1 = er1;
  s += __shfl_xor(s, 1);  s1 += __shfl_xor(s1, 1);
  s += __shfl_xor(s, 2);  s1 += __shfl_xor(s1, 2);
  s += __shfl_xor(s, 4);  s1 += __shfl_xor(s1, 4);
  s += __shfl_xor(s, 8);  s1 += __shfl_xor(s1, 8);
  s += __shfl_xor(s, 16); s1 += __shfl_xor(s1, 16);
  if (lane == 0) {
    atomicAdd(&fw [k * 64 + b], s);      // two waves (ph=0,1) contribute
    atomicAdd(&f1w[k * 64 + b], s1);
  }

  // -------- fused finalize: last block computes pull/push ----------
  __threadfence();
  if (tid == 0) isLast = (atomicAdd(done, 1u) == (unsigned)(KCLS * 32 - 1));
  __syncthreads();
  if (isLast) {
    __threadfence();
    int yv = ycls[lane];
    float pull = 0.f, push = 0.f;
    for (int k2 = w; k2 < KCLS; k2 += 4) {
      float fv  = __hip_atomic_load(&fw [k2 * 64 + lane], __ATOMIC_RELAXED, __HIP_MEMORY_SCOPE_AGENT);
      float f1v = __hip_atomic_load(&f1w[k2 * 64 + lane], __ATOMIC_RELAXED, __HIP_MEMORY_SCOPE_AGENT);
      bool eq = (yv == k2);
      bool cb = (!eq) && (fv < 10000.f);
      float s1 = eq ? f1v : 0.f, ne = eq ? 1.f : 0.f;
      float sv = cb ? fv  : 0.f, nc = cb ? 1.f : 0.f;
      #pragma unroll
      for (int o = 1; o < 64; o <<= 1) {
        s1 += __shfl_xor(s1, o); ne += __shfl_xor(ne, o);
        sv += __shfl_xor(sv, o); nc += __shfl_xor(nc, o);
      }
      if (lane == 0) {
        if (ne > 0.f) pull += s1 / ne;
        if (nc > 0.f) push += sv / nc;
      }
    }
    if (lane == 0) {
      atomicAdd(&out2[0], pull);
      atomicAdd(&out2[1], push);
    }
  }
}

extern "C" void kernel_launch(void* const* d_in, const int* in_sizes, int n_in,
                              void* d_out, int out_size, void* d_ws, size_t ws_size,
                              hipStream_t stream) {
  const float* x     = (const float*)d_in[0];
  const int*   ycls  = (const int*)d_in[1];
  const float* W1    = (const float*)d_in[4];
  const float* W2    = (const float*)d_in[5];
  const float* W3    = (const float*)d_in[6];
  const float* prot  = (const float*)d_in[7];
  const float* prot1 = (const float*)d_in[8];
  float* out = (float*)d_out;

  char* ws = (char*)d_ws;
  u16*  xFb = (u16*)(ws);                        // 4,194,304 B
  u16*  W1F = (u16*)(ws + 4194304);              // 6,553,600 B
  u16*  W2F = (u16*)(ws + 10747904);             // 1,638,400 B
  u16*  W3F = (u16*)(ws + 12386304);             //   819,200 B
  float* fw  = (float*)(ws + 13205504);          // 25,600 B
  float* f1w = (float*)(ws + 13231104);          // 25,600 B (contiguous with fw)
  unsigned* done = (unsigned*)(ws + 13256704);   // 4 B

  prep<<<1625, 256, 0, stream>>>(x, W1, W2, W3, xFb, W1F, W2F, W3F,
                                 fw, done, out + 819200);
  cssr_main<<<KCLS * 32, 256, 0, stream>>>(W1F, W2F, W3F, xFb, prot, prot1, ycls,
                                           out, fw, f1w, done, out + 819200);
}

// Round 6
// 143.255 us; speedup vs baseline: 2.9611x; 2.9611x over previous
//
#include <hip/hip_runtime.h>

typedef short  s16x8  __attribute__((ext_vector_type(8)));
typedef float  f32x16 __attribute__((ext_vector_type(16)));
typedef unsigned short u16;
typedef unsigned long long u64b;

#define MFMA32(a,b,c) __builtin_amdgcn_mfma_f32_32x32x16_bf16((a),(b),(c),0,0,0)
#define KCLS 100

__device__ __forceinline__ u16 f2bf(float f) {
  return (u16)(__builtin_bit_cast(unsigned, f) >> 16);   // trunc; error budget huge
}

__device__ __forceinline__ float tanh_fast(float x) {
  float e = __builtin_amdgcn_exp2f(x * 2.8853900817779268f);
  return 1.0f - 2.0f * __builtin_amdgcn_rcpf(e + 1.0f);
}

__device__ __forceinline__ void ld_lds16(const void* g, void* l) {
  __builtin_amdgcn_global_load_lds(
      (const __attribute__((address_space(1))) unsigned char*)g,
      (__attribute__((address_space(3))) unsigned char*)l, 16, 0, 0);
}

// ============ prep: emit fragment-ordered bf16 tensors + zero accumulators ============
// Fragment = 1 KB: [lane64][8 bf16]; lane&31 = row/col-in-tile, lane>>5 = k-half.
// xF  [b][frag = gks*2+ph]   p = ph*32+(lane&31), c = gks*16+(lane>>5)*8+j
// W1F [k][frag = gks*2+mt]   m = mt*32+(lane&31), c as above
// W2F [k][frag = kb*4+m4]    m = m4*32+(lane&31), c = kb*16+(lane>>5)*8+j
// W3F [k][frag = kb]         m = lane&31,         c = kb*16+(lane>>5)*8+j
__global__ void prep(const float* __restrict__ x, const float* __restrict__ w1,
                     const float* __restrict__ w2, const float* __restrict__ w3,
                     u16* __restrict__ xF, u16* __restrict__ W1F,
                     u16* __restrict__ W2F, u16* __restrict__ W3F,
                     float* __restrict__ fz, float* __restrict__ out2) {
  __shared__ float tile[64][65];
  const int bid = blockIdx.x, t = threadIdx.x;
  if (bid == 0 && t < 2) out2[t] = 0.f;
  if (bid < 512) {                                // ---- x: block = (b, ck) ----
    const int b = bid >> 3, ck = bid & 7;
    #pragma unroll
    for (int j = 0; j < 4; j++) {                 // coalesced fp32 tile (64c x 64p)
      int e4 = j * 1024 + t * 4;
      int c = e4 >> 6, p0 = e4 & 63;
      float4 v = *(const float4*)(x + ((size_t)b * 512 + ck * 64 + c) * 64 + p0);
      tile[c][p0] = v.x; tile[c][p0 + 1] = v.y; tile[c][p0 + 2] = v.z; tile[c][p0 + 3] = v.w;
    }
    __syncthreads();
    #pragma unroll
    for (int i = 0; i < 2; i++) {                 // 512 16B-slots
      int s = i * 256 + t;
      int ksl = s >> 7, ph = (s >> 6) & 1, lane = s & 63;
      int cb = ksl * 16 + (lane >> 5) * 8, pp = ph * 32 + (lane & 31);
      u16 o[8];
      #pragma unroll
      for (int jj = 0; jj < 8; jj++) o[jj] = f2bf(tile[cb + jj][pp]);
      *(uint4*)(xF + (((size_t)b * 64 + (ck * 4 + ksl) * 2 + ph) * 512) + lane * 8) = *(uint4*)o;
    }
  } else if (bid < 1312) {                        // ---- W1: 6400 frags ----
    int base = (bid - 512) * 512;
    #pragma unroll
    for (int i = 0; i < 2; i++) {
      int s = base + i * 256 + t;
      int frag = s >> 6, lane = s & 63;
      int k = frag >> 6, fr = frag & 63;
      int m = (fr & 1) * 32 + (lane & 31);
      int c0 = (fr >> 1) * 16 + (lane >> 5) * 8;
      const float* src = w1 + ((size_t)k * 64 + m) * 512 + c0;
      float4 a = *(const float4*)src, b4 = *(const float4*)(src + 4);
      u16 o[8] = { f2bf(a.x), f2bf(a.y), f2bf(a.z), f2bf(a.w),
                   f2bf(b4.x), f2bf(b4.y), f2bf(b4.z), f2bf(b4.w) };
      *(uint4*)(W1F + ((size_t)frag * 512) + lane * 8) = *(uint4*)o;
    }
  } else if (bid < 1512) {                        // ---- W2: 1600 frags ----
    int base = (bid - 1312) * 512;
    #pragma unroll
    for (int i = 0; i < 2; i++) {
      int s = base + i * 256 + t;
      int frag = s >> 6, lane = s & 63;
      int k = frag >> 4, fr = frag & 15;
      int m = (fr & 3) * 32 + (lane & 31);
      int c0 = (fr >> 2) * 16 + (lane >> 5) * 8;
      const float* src = w2 + ((size_t)k * 128 + m) * 64 + c0;
      float4 a = *(const float4*)src, b4 = *(const float4*)(src + 4);
      u16 o[8] = { f2bf(a.x), f2bf(a.y), f2bf(a.z), f2bf(a.w),
                   f2bf(b4.x), f2bf(b4.y), f2bf(b4.z), f2bf(b4.w) };
      *(uint4*)(W2F + ((size_t)frag * 512) + lane * 8) = *(uint4*)o;
    }
  } else if (bid < 1612) {                        // ---- W3: 800 frags ----
    int base = (bid - 1512) * 512;
    #pragma unroll
    for (int i = 0; i < 2; i++) {
      int s = base + i * 256 + t;
      int frag = s >> 6, lane = s & 63;
      int k = frag >> 3, kb = frag & 7;
      int m = lane & 31;
      int c0 = kb * 16 + (lane >> 5) * 8;
      const float* src = w3 + ((size_t)k * 32 + m) * 128 + c0;
      float4 a = *(const float4*)src, b4 = *(const float4*)(src + 4);
      u16 o[8] = { f2bf(a.x), f2bf(a.y), f2bf(a.z), f2bf(a.w),
                   f2bf(b4.x), f2bf(b4.y), f2bf(b4.z), f2bf(b4.w) };
      *(uint4*)(W3F + ((size_t)frag * 512) + lane * 8) = *(uint4*)o;
    }
  } else {                                        // ---- zero fw/f1w (12800 floats) ----
    int i4 = (bid - 1612) * 256 + t;
    if (i4 < 3200) {
      float4 z = {0.f, 0.f, 0.f, 0.f};
      *(float4*)(fz + (size_t)i4 * 4) = z;
    }
  }
}

// ============ main: block = (k-pair, b); waves = (kk, mt); 32 KB LDS ============
// Stage-1 x staged via global_load_lds in 4 dbuf'd 16 KB chunks; 16 MFMAs/wave
// per barrier interval (round 4 had 4 — its measured 40% stall was the drain).
__global__ __launch_bounds__(256, 4) void cssr_main(
    const u16* __restrict__ W1F, const u16* __restrict__ W2F, const u16* __restrict__ W3F,
    const u16* __restrict__ xF, const float* __restrict__ protos,
    const float* __restrict__ protos1, float* __restrict__ out,
    float* __restrict__ fw, float* __restrict__ f1w)
{
  __shared__ u16 pool[16384];            // 32 KB total
  // buf[pb] = pool + pb*8192 : 16 frags [gksl*2+ph][512]  (x dbuf)
  // h1f (after stage 1) = pool[0:8192]  : [kk][kb*2+nh][512]
  // h2f (after stage 2) = pool[0:16384] : [kk][kb2*2+nh][512] (kk*8192 base)

  const int bid = blockIdx.x;
  const int kp = bid >> 6, b = bid & 63;
  const int tid = threadIdx.x, w = tid >> 6, lane = tid & 63;
  const int nhalf = lane >> 5, nn = lane & 31;
  const int kk = w >> 1, mt = w & 1;
  const int k = kp * 2 + kk;

  const u16* xb = xF + ((size_t)b * 64) * 512;

  // ---------------- stage 1: h1 = tanh(W1[k] @ x[b])  per-wave M=32 N=64 K=512 ----
  #pragma unroll
  for (int i = 0; i < 4; i++) {          // chunk 0: wave stages frags f = w*4+i
    int f = w * 4 + i, gksl = f >> 1, ph = f & 1;
    ld_lds16(xb + ((size_t)(gksl * 2 + ph)) * 512 + lane * 8, &pool[f * 512]);
  }
  __syncthreads();

  f32x16 acc1[2] = {};
  for (int ci = 0; ci < 4; ci++) {
    const int pb = ci & 1;
    if (ci < 3) {
      #pragma unroll
      for (int i = 0; i < 4; i++) {
        int f = w * 4 + i, gksl = f >> 1, ph = f & 1;
        ld_lds16(xb + ((size_t)(((ci + 1) * 8 + gksl) * 2 + ph)) * 512 + lane * 8,
                 &pool[(pb ^ 1) * 8192 + f * 512]);
      }
    }
    #pragma unroll
    for (int ksl = 0; ksl < 8; ksl++) {
      s16x8 A = *(const s16x8*)(W1F + (((size_t)k * 64 + (ci * 8 + ksl) * 2 + mt) * 512) + lane * 8);
      #pragma unroll
      for (int nt = 0; nt < 2; nt++) {
        s16x8 B = *(const s16x8*)&pool[pb * 8192 + (ksl * 2 + nt) * 512 + lane * 8];
        acc1[nt] = MFMA32(A, B, acc1[nt]);
      }
    }
    __syncthreads();
  }

  // handoff 1: C/D (m = mt*32 + q+8g+4*nhalf, n = nt*32+nn) -> h1f[kk][kb*2+nt]
  #pragma unroll
  for (int nt = 0; nt < 2; nt++) {
    #pragma unroll
    for (int g = 0; g < 4; g++) {
      u16 hv[4];
      #pragma unroll
      for (int q = 0; q < 4; q++) hv[q] = f2bf(tanh_fast(acc1[nt][g * 4 + q]));
      int kb = mt * 2 + (g >> 1);
      int tl = (g & 1) * 32 + nn;
      *(u64b*)&pool[kk * 4096 + (kb * 2 + nt) * 512 + tl * 8 + nhalf * 4] = *(u64b*)hv;
    }
  }
  __syncthreads();

  // ---------------- stage 2: h2 = tanh(W2[k] @ h1)  per-wave M=64 N=64 K=64 ----
  f32x16 acc2[2][2] = {};
  #pragma unroll
  for (int kb = 0; kb < 4; kb++) {
    s16x8 A0 = *(const s16x8*)(W2F + (((size_t)k * 16 + kb * 4 + mt * 2 + 0) * 512) + lane * 8);
    s16x8 A1 = *(const s16x8*)(W2F + (((size_t)k * 16 + kb * 4 + mt * 2 + 1) * 512) + lane * 8);
    #pragma unroll
    for (int nh = 0; nh < 2; nh++) {
      s16x8 B = *(const s16x8*)&pool[kk * 4096 + (kb * 2 + nh) * 512 + lane * 8];
      acc2[0][nh] = MFMA32(A0, B, acc2[0][nh]);
      acc2[1][nh] = MFMA32(A1, B, acc2[1][nh]);
    }
  }
  __syncthreads();   // all h1f reads done before h2f overlays the full pool

  // handoff 2: m = (mt*2+m4l)*32 + q+8g+4*nhalf -> kb2 = mt*4 + m4l*2 + (g>>1)
  #pragma unroll
  for (int m4l = 0; m4l < 2; m4l++) {
    #pragma unroll
    for (int nh = 0; nh < 2; nh++) {
      #pragma unroll
      for (int g = 0; g < 4; g++) {
        u16 hv[4];
        #pragma unroll
        for (int q = 0; q < 4; q++) hv[q] = f2bf(tanh_fast(acc2[m4l][nh][g * 4 + q]));
        int kb2 = mt * 4 + m4l * 2 + (g >> 1);
        int tl  = (g & 1) * 32 + nn;
        *(u64b*)&pool[kk * 8192 + (kb2 * 2 + nh) * 512 + tl * 8 + nhalf * 4] = *(u64b*)hv;
      }
    }
  }
  __syncthreads();

  // ---------------- stage 3: lt = tanh(W3[k] @ h2)  per-wave M=32 N=32 K=128 ----
  // wave role: (kk, ph = mt)
  f32x16 acc3 = {};
  #pragma unroll
  for (int kb = 0; kb < 8; kb++) {
    s16x8 A = *(const s16x8*)(W3F + (((size_t)k * 8 + kb) * 512) + lane * 8);
    s16x8 B = *(const s16x8*)&pool[kk * 8192 + (kb * 2 + mt) * 512 + lane * 8];
    acc3 = MFMA32(A, B, acc3);
  }

  // ---------------- distances, clip, logits, f / f1 ----------------
  const int p = mt * 32 + nn;
  const float* pr  = protos  + (size_t)k * 2048;
  const float* pr1 = protos1 + (size_t)k * 2048;
  float d2 = 0.f, d21 = 0.f;
  #pragma unroll
  for (int g = 0; g < 4; g++) {
    #pragma unroll
    for (int q = 0; q < 4; q++) {
      int m = q + 8 * g + 4 * nhalf;
      float lt = tanh_fast(acc3[g * 4 + q]);
      float d = lt - pr [m * 64 + p];  d2  += d * d;
      float e = lt - pr1[m * 64 + p];  d21 += e * e;
    }
  }
  d2 += __shfl_xor(d2, 32); d21 += __shfl_xor(d21, 32);
  float er  = fminf(fmaxf(d2  * -0.1f, -100.f), 100.f);
  float er1 = fminf(fmaxf(d21 * -0.1f, -100.f), 100.f);
  if (nhalf == 0) {
    out[(size_t)b * 6400 + k * 64 + p]          = er;
    out[409600 + (size_t)b * 6400 + k * 64 + p] = er1;
  }
  float s = er, s1 = er1;
  s += __shfl_xor(s, 1);  s1 += __shfl_xor(s1, 1);
  s += __shfl_xor(s, 2);  s1 += __shfl_xor(s1, 2);
  s += __shfl_xor(s, 4);  s1 += __shfl_xor(s1, 4);
  s += __shfl_xor(s, 8);  s1 += __shfl_xor(s1, 8);
  s += __shfl_xor(s, 16); s1 += __shfl_xor(s1, 16);
  if (lane == 0) {
    atomicAdd(&fw [k * 64 + b], s);    // two waves (mt=0,1) contribute per (k,b)
    atomicAdd(&f1w[k * 64 + b], s1);
  }
}

// ============ finalize: per-k block, atomicAdd into out2 (zeroed in prep) ============
__global__ void finalize(const float* __restrict__ f, const float* __restrict__ f1,
                         const int* __restrict__ ycls, float* __restrict__ out2) {
  const int k = blockIdx.x, b = threadIdx.x;
  float fv = f[k * 64 + b], f1v = f1[k * 64 + b];
  bool eq = (ycls[b] == k);
  bool cb = (!eq) && (fv < 10000.f);
  float s1 = eq ? f1v : 0.f, ne = eq ? 1.f : 0.f;
  float s  = cb ? fv  : 0.f, nc = cb ? 1.f : 0.f;
  #pragma unroll
  for (int o = 1; o < 64; o <<= 1) {
    s1 += __shfl_xor(s1, o); ne += __shfl_xor(ne, o);
    s  += __shfl_xor(s,  o); nc += __shfl_xor(nc, o);
  }
  if (b == 0) {
    if (ne > 0.f) atomicAdd(&out2[0], s1 / ne);
    if (nc > 0.f) atomicAdd(&out2[1], s / nc);
  }
}

extern "C" void kernel_launch(void* const* d_in, const int* in_sizes, int n_in,
                              void* d_out, int out_size, void* d_ws, size_t ws_size,
                              hipStream_t stream) {
  const float* x     = (const float*)d_in[0];
  const int*   ycls  = (const int*)d_in[1];
  const float* W1    = (const float*)d_in[4];
  const float* W2    = (const float*)d_in[5];
  const float* W3    = (const float*)d_in[6];
  const float* prot  = (const float*)d_in[7];
  const float* prot1 = (const float*)d_in[8];
  float* out = (float*)d_out;

  char* ws = (char*)d_ws;
  u16*  xFb = (u16*)(ws);                        // 4,194,304 B
  u16*  W1F = (u16*)(ws + 4194304);              // 6,553,600 B
  u16*  W2F = (u16*)(ws + 10747904);             // 1,638,400 B
  u16*  W3F = (u16*)(ws + 12386304);             //   819,200 B
  float* fw  = (float*)(ws + 13205504);          // 25,600 B
  float* f1w = (float*)(ws + 13231104);          // 25,600 B (contiguous with fw)

  prep<<<1625, 256, 0, stream>>>(x, W1, W2, W3, xFb, W1F, W2F, W3F,
                                 fw, out + 819200);
  cssr_main<<<50 * 64, 256, 0, stream>>>(W1F, W2F, W3F, xFb, prot, prot1,
                                         out, fw, f1w);
  finalize<<<KCLS, 64, 0, stream>>>(fw, f1w, ycls, out + 819200);
}